// Round 1
// baseline (785.669 us; speedup 1.0000x reference)
//
#include <hip/hip_runtime.h>
#include <cmath>

typedef __attribute__((ext_vector_type(8))) short bf16x8;
typedef __attribute__((ext_vector_type(4))) float f32x4;

__device__ __forceinline__ short f2bf(float f) {
    unsigned u = __builtin_bit_cast(unsigned, f);
    u += 0x7fff + ((u >> 16) & 1);   // RNE
    return (short)(u >> 16);
}

// ---------------------------------------------------------------------------
// Counting sort of edges by destination.
// ---------------------------------------------------------------------------
__global__ __launch_bounds__(256)
void hist_kernel(const int* __restrict__ dst, int* __restrict__ counts, int E)
{
    int e = blockIdx.x * 256 + threadIdx.x;
    if (e < E) atomicAdd(&counts[dst[e]], 1);
}

// --- coalesced 3-phase scan over N counts -> offsets[0..N] & cursor ---
#define SCAN_B 256

// P1: per-block exclusive scan (into offsets) + per-block total
__global__ __launch_bounds__(SCAN_B)
void scan_p1_kernel(const int* __restrict__ counts, int* __restrict__ offsets,
                    int* __restrict__ blockSums, int N)
{
    __shared__ int sh[SCAN_B];
    const int t = threadIdx.x;
    const int i = blockIdx.x * SCAN_B + t;
    int v = (i < N) ? counts[i] : 0;
    sh[t] = v;
    __syncthreads();
    for (int d = 1; d < SCAN_B; d <<= 1) {
        int u = (t >= d) ? sh[t - d] : 0;
        __syncthreads();
        sh[t] += u;
        __syncthreads();
    }
    if (i < N) offsets[i] = sh[t] - v;           // local exclusive
    if (t == SCAN_B - 1) blockSums[blockIdx.x] = sh[SCAN_B - 1];
}

// P2: single tiny block: exclusive scan of blockSums (nblk <= 256)
__global__ __launch_bounds__(SCAN_B)
void scan_p2_kernel(int* __restrict__ blockSums, int nblk)
{
    __shared__ int sh[SCAN_B];
    const int t = threadIdx.x;
    int v = (t < nblk) ? blockSums[t] : 0;
    sh[t] = v;
    __syncthreads();
    for (int d = 1; d < SCAN_B; d <<= 1) {
        int u = (t >= d) ? sh[t - d] : 0;
        __syncthreads();
        sh[t] += u;
        __syncthreads();
    }
    if (t < nblk) blockSums[t] = sh[t] - v;      // exclusive
}

// P3: add block offset, emit offsets & cursor (coalesced)
__global__ __launch_bounds__(SCAN_B)
void scan_p3_kernel(int* __restrict__ offsets, const int* __restrict__ blockSums,
                    int* __restrict__ cursor, int N, int E)
{
    const int i = blockIdx.x * SCAN_B + threadIdx.x;
    if (i < N) {
        int o = offsets[i] + blockSums[blockIdx.x];
        offsets[i] = o;
        cursor[i]  = o;
    }
    if (i == 0) offsets[N] = E;
}

__global__ __launch_bounds__(256)
void scatter_perm_kernel(const int* __restrict__ dst, int* __restrict__ cursor,
                         int* __restrict__ perm, int E)
{
    int e = blockIdx.x * 256 + threadIdx.x;
    if (e < E) {
        int p = atomicAdd(&cursor[dst[e]], 1);
        perm[p] = e;
    }
}

// ---------------------------------------------------------------------------
// Fused gather + 3-layer MLP, bf16 MFMA.
// Wave wv owns output rows m0..m0+15 of the 128-row block tile; it gathers
// edge sums for exactly those rows directly into its At slots (no edge_sum
// global round-trip, no separate gather dispatch).
// ---------------------------------------------------------------------------
__device__ __forceinline__ void stage_W(const float* __restrict__ W, int krow0,
                                        short* __restrict__ Wt, int tid)
{
    #pragma unroll
    for (int i = 0; i < 16; ++i) {
        int p = tid + i * 512;
        int n = p & 127;
        int k = (p >> 7) << 1;
        float a = W[(size_t)(krow0 + k) * 128 + n];
        float b = W[(size_t)(krow0 + k + 1) * 128 + n];
        int grp = (k >> 3) ^ (n & 15);
        ushort2 s;
        s.x = (unsigned short)f2bf(a);
        s.y = (unsigned short)f2bf(b);
        *reinterpret_cast<ushort2*>(&Wt[n * 128 + grp * 8 + (k & 7)]) = s;
    }
}

__global__ __launch_bounds__(512, 2)
void fused_mlp_kernel(const float* __restrict__ x,
                      const float* __restrict__ edge_attr,
                      const int* __restrict__ perm,
                      const int* __restrict__ offsets,
                      const float* __restrict__ W0, const float* __restrict__ b0,
                      const float* __restrict__ W2, const float* __restrict__ b2,
                      const float* __restrict__ W3, const float* __restrict__ b3,
                      float* __restrict__ out, int N)
{
    __shared__ short At[128 * 128];
    __shared__ short Wt[128 * 128];

    const int tid  = threadIdx.x;
    const int lane = tid & 63;
    const int wv   = tid >> 6;
    const int l15  = lane & 15;
    const int quad = lane >> 4;
    const int m0   = wv * 16;
    const int blockRow = blockIdx.x * 128;
    const int half32 = lane >> 5;     // 0: lanes 0-31, 1: lanes 32-63
    const int li     = lane & 31;     // channel-quad index within half

    f32x4 acc[8];
    #pragma unroll
    for (int nt = 0; nt < 8; ++nt) acc[nt] = (f32x4){0.f, 0.f, 0.f, 0.f};

    // ---------------- half 0: x @ W0[0:128] ----------------
    #pragma unroll
    for (int i = 0; i < 8; ++i) {
        int f  = tid + i * 512;
        int r  = f >> 5;
        int c4 = (f & 31) << 2;
        int g  = blockRow + r; if (g >= N) g = N - 1;
        const float4 v = *reinterpret_cast<const float4*>(&x[(size_t)g * 128 + c4]);
        int grp = (c4 >> 3) ^ (r & 15);
        ushort4 s;
        s.x = (unsigned short)f2bf(v.x);
        s.y = (unsigned short)f2bf(v.y);
        s.z = (unsigned short)f2bf(v.z);
        s.w = (unsigned short)f2bf(v.w);
        *reinterpret_cast<ushort4*>(&At[r * 128 + grp * 8 + (c4 & 7)]) = s;
    }
    stage_W(W0, 0, Wt, tid);
    __syncthreads();
    #pragma unroll
    for (int ks = 0; ks < 4; ++ks) {
        int g = ks * 4 + quad;
        int so = ((g ^ l15) << 3);
        bf16x8 a = *reinterpret_cast<bf16x8*>(&At[(m0 + l15) * 128 + so]);
        #pragma unroll
        for (int nt = 0; nt < 8; ++nt) {
            bf16x8 b = *reinterpret_cast<bf16x8*>(&Wt[(nt * 16 + l15) * 128 + so]);
            acc[nt] = __builtin_amdgcn_mfma_f32_16x16x32_bf16(a, b, acc[nt], 0, 0, 0);
        }
    }
    __syncthreads();   // all waves done reading At/Wt before restage

    // ---------------- half 1: edge_sum @ W0[128:256], gathered in-kernel ----
    stage_W(W0, 128, Wt, tid);
    for (int r = 0; r < 16; ++r) {
        const int g = blockRow + m0 + r;
        float4 a4 = make_float4(0.f, 0.f, 0.f, 0.f);
        if (g < N) {
            const int beg = offsets[g];
            const int end = offsets[g + 1];
            for (int base = beg; base < end; base += 64) {
                const int m = (end - base < 64) ? (end - base) : 64;
                int eid = 0;
                if (lane < m) eid = perm[base + lane];
                const int pairs = (m + 1) >> 1;
                #pragma unroll 4
                for (int j = 0; j < pairs; ++j) {
                    const int idx = 2 * j + half32;
                    const int e = __shfl(eid, idx, 64);
                    if (idx < m) {
                        const float4 v = *reinterpret_cast<const float4*>(
                            &edge_attr[(size_t)e * 128 + li * 4]);
                        a4.x += v.x; a4.y += v.y; a4.z += v.z; a4.w += v.w;
                    }
                }
            }
        }
        // fold upper half into lower half, write this wave's own At row
        float4 o;
        o.x = __shfl(a4.x, li + 32, 64);
        o.y = __shfl(a4.y, li + 32, 64);
        o.z = __shfl(a4.z, li + 32, 64);
        o.w = __shfl(a4.w, li + 32, 64);
        if (half32 == 0) {
            a4.x += o.x; a4.y += o.y; a4.z += o.z; a4.w += o.w;
            const int rg  = m0 + r;                 // row in tile (this wave's)
            const int grp = (li >> 1) ^ (rg & 15);  // channel group swizzle
            ushort4 s;
            s.x = (unsigned short)f2bf(a4.x);
            s.y = (unsigned short)f2bf(a4.y);
            s.z = (unsigned short)f2bf(a4.z);
            s.w = (unsigned short)f2bf(a4.w);
            *reinterpret_cast<ushort4*>(&At[rg * 128 + grp * 8 + (li & 1) * 4]) = s;
        }
    }
    __syncthreads();
    #pragma unroll
    for (int ks = 0; ks < 4; ++ks) {
        int g = ks * 4 + quad;
        int so = ((g ^ l15) << 3);
        bf16x8 a = *reinterpret_cast<bf16x8*>(&At[(m0 + l15) * 128 + so]);
        #pragma unroll
        for (int nt = 0; nt < 8; ++nt) {
            bf16x8 b = *reinterpret_cast<bf16x8*>(&Wt[(nt * 16 + l15) * 128 + so]);
            acc[nt] = __builtin_amdgcn_mfma_f32_16x16x32_bf16(a, b, acc[nt], 0, 0, 0);
        }
    }

    // ---------------- layer 2 ----------------
    __syncthreads();
    #pragma unroll
    for (int nt = 0; nt < 8; ++nt) {
        float bv = b0[nt * 16 + l15];
        #pragma unroll
        for (int r = 0; r < 4; ++r) {
            float v = acc[nt][r] + bv;
            v = (v > 0.f) ? v : (__expf(v) - 1.f);
            int m = m0 + quad * 4 + r;
            int c = nt * 16 + l15;
            int grp = (c >> 3) ^ (m & 15);
            At[m * 128 + grp * 8 + (c & 7)] = f2bf(v);
        }
        acc[nt] = (f32x4){0.f, 0.f, 0.f, 0.f};
    }
    stage_W(W2, 0, Wt, tid);
    __syncthreads();

    #pragma unroll
    for (int ks = 0; ks < 4; ++ks) {
        int g = ks * 4 + quad;
        int so = ((g ^ l15) << 3);
        bf16x8 a = *reinterpret_cast<bf16x8*>(&At[(m0 + l15) * 128 + so]);
        #pragma unroll
        for (int nt = 0; nt < 8; ++nt) {
            bf16x8 b = *reinterpret_cast<bf16x8*>(&Wt[(nt * 16 + l15) * 128 + so]);
            acc[nt] = __builtin_amdgcn_mfma_f32_16x16x32_bf16(a, b, acc[nt], 0, 0, 0);
        }
    }

    // ---------------- layer 3 ----------------
    __syncthreads();
    #pragma unroll
    for (int nt = 0; nt < 8; ++nt) {
        float bv = b2[nt * 16 + l15];
        #pragma unroll
        for (int r = 0; r < 4; ++r) {
            float v = acc[nt][r] + bv;
            v = (v > 0.f) ? v : (__expf(v) - 1.f);
            int m = m0 + quad * 4 + r;
            int c = nt * 16 + l15;
            int grp = (c >> 3) ^ (m & 15);
            At[m * 128 + grp * 8 + (c & 7)] = f2bf(v);
        }
        acc[nt] = (f32x4){0.f, 0.f, 0.f, 0.f};
    }
    stage_W(W3, 0, Wt, tid);
    __syncthreads();

    #pragma unroll
    for (int ks = 0; ks < 4; ++ks) {
        int g = ks * 4 + quad;
        int so = ((g ^ l15) << 3);
        bf16x8 a = *reinterpret_cast<bf16x8*>(&At[(m0 + l15) * 128 + so]);
        #pragma unroll
        for (int nt = 0; nt < 8; ++nt) {
            bf16x8 b = *reinterpret_cast<bf16x8*>(&Wt[(nt * 16 + l15) * 128 + so]);
            acc[nt] = __builtin_amdgcn_mfma_f32_16x16x32_bf16(a, b, acc[nt], 0, 0, 0);
        }
    }

    #pragma unroll
    for (int nt = 0; nt < 8; ++nt) {
        float bv = b3[nt * 16 + l15];
        #pragma unroll
        for (int r = 0; r < 4; ++r) {
            int gr = blockRow + m0 + quad * 4 + r;
            if (gr < N) out[(size_t)gr * 128 + nt * 16 + l15] = acc[nt][r] + bv;
        }
    }
}

extern "C" void kernel_launch(void* const* d_in, const int* in_sizes, int n_in,
                              void* d_out, int out_size, void* d_ws, size_t ws_size,
                              hipStream_t stream)
{
    const float* x     = (const float*)d_in[0];
    const int*   eidx  = (const int*)d_in[1];   // row 0 = dst
    const float* eattr = (const float*)d_in[2];
    const float* W0 = (const float*)d_in[3];
    const float* b0 = (const float*)d_in[4];
    const float* W2 = (const float*)d_in[5];
    const float* b2 = (const float*)d_in[6];
    const float* W3 = (const float*)d_in[7];
    const float* b3 = (const float*)d_in[8];
    float* out = (float*)d_out;

    const int N = in_sizes[0] / 128;   // 50000
    const int E = in_sizes[2] / 128;   // 800000

    int* counts    = (int*)d_ws;                 // [N]
    int* offsets   = counts + N;                 // [N+1]
    int* cursor    = offsets + (N + 1);          // [N]
    int* blockSums = cursor + N;                 // [<=256]
    int* perm      = blockSums + 256;            // [E]

    hipMemsetAsync(counts, 0, (size_t)N * sizeof(int), stream);

    const int eblocks = (E + 255) / 256;
    const int nblk    = (N + SCAN_B - 1) / SCAN_B;   // 196 <= 256

    hist_kernel<<<eblocks, 256, 0, stream>>>(eidx, counts, E);
    scan_p1_kernel<<<nblk, SCAN_B, 0, stream>>>(counts, offsets, blockSums, N);
    scan_p2_kernel<<<1, SCAN_B, 0, stream>>>(blockSums, nblk);
    scan_p3_kernel<<<nblk, SCAN_B, 0, stream>>>(offsets, blockSums, cursor, N, E);
    scatter_perm_kernel<<<eblocks, 256, 0, stream>>>(eidx, cursor, perm, E);

    int mblocks = (N + 127) / 128;
    fused_mlp_kernel<<<mblocks, 512, 0, stream>>>(x, eattr, perm, offsets,
                                                  W0, b0, W2, b2, W3, b3, out, N);
}

// Round 2
// 699.649 us; speedup vs baseline: 1.1229x; 1.1229x over previous
//
#include <hip/hip_runtime.h>
#include <cmath>

typedef __attribute__((ext_vector_type(8))) short bf16x8;
typedef __attribute__((ext_vector_type(4))) float f32x4;

__device__ __forceinline__ short f2bf(float f) {
    unsigned u = __builtin_bit_cast(unsigned, f);
    u += 0x7fff + ((u >> 16) & 1);   // RNE
    return (short)(u >> 16);
}

// ---------------------------------------------------------------------------
// Counting sort of edges by destination.
// ---------------------------------------------------------------------------
__global__ __launch_bounds__(256)
void hist_kernel(const int* __restrict__ dst, int* __restrict__ counts, int E)
{
    int e = blockIdx.x * 256 + threadIdx.x;
    if (e < E) atomicAdd(&counts[dst[e]], 1);
}

// --- coalesced 3-phase scan over N counts -> offsets[0..N] & cursor ---
#define SCAN_B 256

__global__ __launch_bounds__(SCAN_B)
void scan_p1_kernel(const int* __restrict__ counts, int* __restrict__ offsets,
                    int* __restrict__ blockSums, int N)
{
    __shared__ int sh[SCAN_B];
    const int t = threadIdx.x;
    const int i = blockIdx.x * SCAN_B + t;
    int v = (i < N) ? counts[i] : 0;
    sh[t] = v;
    __syncthreads();
    for (int d = 1; d < SCAN_B; d <<= 1) {
        int u = (t >= d) ? sh[t - d] : 0;
        __syncthreads();
        sh[t] += u;
        __syncthreads();
    }
    if (i < N) offsets[i] = sh[t] - v;           // local exclusive
    if (t == SCAN_B - 1) blockSums[blockIdx.x] = sh[SCAN_B - 1];
}

__global__ __launch_bounds__(SCAN_B)
void scan_p2_kernel(int* __restrict__ blockSums, int nblk)
{
    __shared__ int sh[SCAN_B];
    const int t = threadIdx.x;
    int v = (t < nblk) ? blockSums[t] : 0;
    sh[t] = v;
    __syncthreads();
    for (int d = 1; d < SCAN_B; d <<= 1) {
        int u = (t >= d) ? sh[t - d] : 0;
        __syncthreads();
        sh[t] += u;
        __syncthreads();
    }
    if (t < nblk) blockSums[t] = sh[t] - v;      // exclusive
}

__global__ __launch_bounds__(SCAN_B)
void scan_p3_kernel(int* __restrict__ offsets, const int* __restrict__ blockSums,
                    int* __restrict__ cursor, int N, int E)
{
    const int i = blockIdx.x * SCAN_B + threadIdx.x;
    if (i < N) {
        int o = offsets[i] + blockSums[blockIdx.x];
        offsets[i] = o;
        cursor[i]  = o;
    }
    if (i == 0) offsets[N] = E;
}

__global__ __launch_bounds__(256)
void scatter_perm_kernel(const int* __restrict__ dst, int* __restrict__ cursor,
                         int* __restrict__ perm, int E)
{
    int e = blockIdx.x * 256 + threadIdx.x;
    if (e < E) {
        int p = atomicAdd(&cursor[dst[e]], 1);
        perm[p] = e;
    }
}

// ---------------------------------------------------------------------------
// Gather-sum: one wave per node (high TLP -> BW-bound, not latency-bound).
// Lanes 0-31 / 32-63 process even/odd edges; each li covers channels
// 4*li..4*li+3 as float4. Output written as bf16 DIRECTLY in the MLP's
// swizzled At-tile layout: esB[tile*16384 + r*128 + grp*8 + (c&7)],
// grp = (c>>3) ^ (r&15). Rows past N emit zeros (clean tail tile).
// ---------------------------------------------------------------------------
__global__ __launch_bounds__(256)
void gather_bf16_kernel(const float* __restrict__ edge_attr,
                        const int* __restrict__ perm,
                        const int* __restrict__ offsets,
                        unsigned short* __restrict__ esB, int N, int total)
{
    const int wid  = (blockIdx.x * 256 + threadIdx.x) >> 6;
    const int lane = threadIdx.x & 63;
    if (wid >= total) return;
    const int half = lane >> 5;
    const int li   = lane & 31;

    float4 acc = make_float4(0.f, 0.f, 0.f, 0.f);
    if (wid < N) {
        const int beg = offsets[wid];
        const int end = offsets[wid + 1];
        for (int base = beg; base < end; base += 64) {
            const int m = (end - base < 64) ? (end - base) : 64;
            int eid = 0;
            if (lane < m) eid = perm[base + lane];
            const int pairs = (m + 1) >> 1;
            #pragma unroll 4
            for (int j = 0; j < pairs; ++j) {
                const int idx = 2 * j + half;
                const int e = __shfl(eid, idx, 64);
                if (idx < m) {
                    const float4 v = *reinterpret_cast<const float4*>(
                        &edge_attr[(size_t)e * 128 + li * 4]);
                    acc.x += v.x; acc.y += v.y; acc.z += v.z; acc.w += v.w;
                }
            }
        }
    }
    // fold upper half into lower half
    float4 o;
    o.x = __shfl(acc.x, li + 32, 64);
    o.y = __shfl(acc.y, li + 32, 64);
    o.z = __shfl(acc.z, li + 32, 64);
    o.w = __shfl(acc.w, li + 32, 64);
    if (half == 0) {
        acc.x += o.x; acc.y += o.y; acc.z += o.z; acc.w += o.w;
        const int r   = wid & 127;
        const int t   = wid >> 7;
        const int grp = (li >> 1) ^ (r & 15);     // c4 = 4*li; grp = (c4>>3)^(r&15)
        ushort4 s;
        s.x = (unsigned short)f2bf(acc.x);
        s.y = (unsigned short)f2bf(acc.y);
        s.z = (unsigned short)f2bf(acc.z);
        s.w = (unsigned short)f2bf(acc.w);
        *reinterpret_cast<ushort4*>(
            &esB[(size_t)t * 16384 + r * 128 + grp * 8 + (li & 1) * 4]) = s;
    }
}

// ---------------------------------------------------------------------------
// Fused 3-layer MLP, bf16 MFMA. Half-1 A-tile arrives pre-swizzled in bf16
// (esB); its 32 KB are loaded into registers BEFORE the half-0 MFMA so the
// HBM latency hides under compute, then dumped linearly into At.
// ---------------------------------------------------------------------------
__device__ __forceinline__ void stage_W(const float* __restrict__ W, int krow0,
                                        short* __restrict__ Wt, int tid)
{
    #pragma unroll
    for (int i = 0; i < 16; ++i) {
        int p = tid + i * 512;
        int n = p & 127;
        int k = (p >> 7) << 1;
        float a = W[(size_t)(krow0 + k) * 128 + n];
        float b = W[(size_t)(krow0 + k + 1) * 128 + n];
        int grp = (k >> 3) ^ (n & 15);
        ushort2 s;
        s.x = (unsigned short)f2bf(a);
        s.y = (unsigned short)f2bf(b);
        *reinterpret_cast<ushort2*>(&Wt[n * 128 + grp * 8 + (k & 7)]) = s;
    }
}

__global__ __launch_bounds__(512, 2)
void fused_mlp_kernel(const float* __restrict__ x,
                      const unsigned short* __restrict__ esB,
                      const float* __restrict__ W0, const float* __restrict__ b0,
                      const float* __restrict__ W2, const float* __restrict__ b2,
                      const float* __restrict__ W3, const float* __restrict__ b3,
                      float* __restrict__ out, int N)
{
    __shared__ short At[128 * 128];
    __shared__ short Wt[128 * 128];

    const int tid  = threadIdx.x;
    const int lane = tid & 63;
    const int wv   = tid >> 6;
    const int l15  = lane & 15;
    const int quad = lane >> 4;
    const int m0   = wv * 16;
    const int blockRow = blockIdx.x * 128;

    f32x4 acc[8];
    #pragma unroll
    for (int nt = 0; nt < 8; ++nt) acc[nt] = (f32x4){0.f, 0.f, 0.f, 0.f};

    // Issue half-1 A-tile loads early (T14 async split): 32 KB linear copy.
    uint4 es[4];
    {
        const uint4* esg = reinterpret_cast<const uint4*>(esB) +
                           (size_t)blockIdx.x * 2048;
        #pragma unroll
        for (int i = 0; i < 4; ++i) es[i] = esg[i * 512 + tid];
    }

    // ---------------- half 0: x @ W0[0:128] ----------------
    #pragma unroll
    for (int i = 0; i < 8; ++i) {
        int f  = tid + i * 512;
        int r  = f >> 5;
        int c4 = (f & 31) << 2;
        int g  = blockRow + r; if (g >= N) g = N - 1;
        const float4 v = *reinterpret_cast<const float4*>(&x[(size_t)g * 128 + c4]);
        int grp = (c4 >> 3) ^ (r & 15);
        ushort4 s;
        s.x = (unsigned short)f2bf(v.x);
        s.y = (unsigned short)f2bf(v.y);
        s.z = (unsigned short)f2bf(v.z);
        s.w = (unsigned short)f2bf(v.w);
        *reinterpret_cast<ushort4*>(&At[r * 128 + grp * 8 + (c4 & 7)]) = s;
    }
    stage_W(W0, 0, Wt, tid);
    __syncthreads();
    #pragma unroll
    for (int ks = 0; ks < 4; ++ks) {
        int g = ks * 4 + quad;
        int so = ((g ^ l15) << 3);
        bf16x8 a = *reinterpret_cast<bf16x8*>(&At[(m0 + l15) * 128 + so]);
        #pragma unroll
        for (int nt = 0; nt < 8; ++nt) {
            bf16x8 b = *reinterpret_cast<bf16x8*>(&Wt[(nt * 16 + l15) * 128 + so]);
            acc[nt] = __builtin_amdgcn_mfma_f32_16x16x32_bf16(a, b, acc[nt], 0, 0, 0);
        }
    }
    __syncthreads();   // all waves done reading At/Wt before restage

    // ---------------- half 1: edge_sum @ W0[128:256] ----------------
    {
        uint4* atv = reinterpret_cast<uint4*>(At);
        #pragma unroll
        for (int i = 0; i < 4; ++i) atv[i * 512 + tid] = es[i];
    }
    stage_W(W0, 128, Wt, tid);
    __syncthreads();
    #pragma unroll
    for (int ks = 0; ks < 4; ++ks) {
        int g = ks * 4 + quad;
        int so = ((g ^ l15) << 3);
        bf16x8 a = *reinterpret_cast<bf16x8*>(&At[(m0 + l15) * 128 + so]);
        #pragma unroll
        for (int nt = 0; nt < 8; ++nt) {
            bf16x8 b = *reinterpret_cast<bf16x8*>(&Wt[(nt * 16 + l15) * 128 + so]);
            acc[nt] = __builtin_amdgcn_mfma_f32_16x16x32_bf16(a, b, acc[nt], 0, 0, 0);
        }
    }

    // ---------------- layer 2 ----------------
    __syncthreads();
    #pragma unroll
    for (int nt = 0; nt < 8; ++nt) {
        float bv = b0[nt * 16 + l15];
        #pragma unroll
        for (int r = 0; r < 4; ++r) {
            float v = acc[nt][r] + bv;
            v = (v > 0.f) ? v : (__expf(v) - 1.f);
            int m = m0 + quad * 4 + r;
            int c = nt * 16 + l15;
            int grp = (c >> 3) ^ (m & 15);
            At[m * 128 + grp * 8 + (c & 7)] = f2bf(v);
        }
        acc[nt] = (f32x4){0.f, 0.f, 0.f, 0.f};
    }
    stage_W(W2, 0, Wt, tid);
    __syncthreads();

    #pragma unroll
    for (int ks = 0; ks < 4; ++ks) {
        int g = ks * 4 + quad;
        int so = ((g ^ l15) << 3);
        bf16x8 a = *reinterpret_cast<bf16x8*>(&At[(m0 + l15) * 128 + so]);
        #pragma unroll
        for (int nt = 0; nt < 8; ++nt) {
            bf16x8 b = *reinterpret_cast<bf16x8*>(&Wt[(nt * 16 + l15) * 128 + so]);
            acc[nt] = __builtin_amdgcn_mfma_f32_16x16x32_bf16(a, b, acc[nt], 0, 0, 0);
        }
    }

    // ---------------- layer 3 ----------------
    __syncthreads();
    #pragma unroll
    for (int nt = 0; nt < 8; ++nt) {
        float bv = b2[nt * 16 + l15];
        #pragma unroll
        for (int r = 0; r < 4; ++r) {
            float v = acc[nt][r] + bv;
            v = (v > 0.f) ? v : (__expf(v) - 1.f);
            int m = m0 + quad * 4 + r;
            int c = nt * 16 + l15;
            int grp = (c >> 3) ^ (m & 15);
            At[m * 128 + grp * 8 + (c & 7)] = f2bf(v);
        }
        acc[nt] = (f32x4){0.f, 0.f, 0.f, 0.f};
    }
    stage_W(W3, 0, Wt, tid);
    __syncthreads();

    #pragma unroll
    for (int ks = 0; ks < 4; ++ks) {
        int g = ks * 4 + quad;
        int so = ((g ^ l15) << 3);
        bf16x8 a = *reinterpret_cast<bf16x8*>(&At[(m0 + l15) * 128 + so]);
        #pragma unroll
        for (int nt = 0; nt < 8; ++nt) {
            bf16x8 b = *reinterpret_cast<bf16x8*>(&Wt[(nt * 16 + l15) * 128 + so]);
            acc[nt] = __builtin_amdgcn_mfma_f32_16x16x32_bf16(a, b, acc[nt], 0, 0, 0);
        }
    }

    #pragma unroll
    for (int nt = 0; nt < 8; ++nt) {
        float bv = b3[nt * 16 + l15];
        #pragma unroll
        for (int r = 0; r < 4; ++r) {
            int gr = blockRow + m0 + quad * 4 + r;
            if (gr < N) out[(size_t)gr * 128 + nt * 16 + l15] = acc[nt][r] + bv;
        }
    }
}

extern "C" void kernel_launch(void* const* d_in, const int* in_sizes, int n_in,
                              void* d_out, int out_size, void* d_ws, size_t ws_size,
                              hipStream_t stream)
{
    const float* x     = (const float*)d_in[0];
    const int*   eidx  = (const int*)d_in[1];   // row 0 = dst
    const float* eattr = (const float*)d_in[2];
    const float* W0 = (const float*)d_in[3];
    const float* b0 = (const float*)d_in[4];
    const float* W2 = (const float*)d_in[5];
    const float* b2 = (const float*)d_in[6];
    const float* W3 = (const float*)d_in[7];
    const float* b3 = (const float*)d_in[8];
    float* out = (float*)d_out;

    const int N = in_sizes[0] / 128;   // 50000
    const int E = in_sizes[2] / 128;   // 800000

    int* counts    = (int*)d_ws;                 // [N]
    int* offsets   = counts + N;                 // [N+1]
    int* cursor    = offsets + (N + 1);          // [N]
    int* blockSums = cursor + N;                 // [<=256]
    int* perm      = blockSums + 256;            // [E]
    uintptr_t p = (uintptr_t)(perm + E);
    p = (p + 255) & ~(uintptr_t)255;
    unsigned short* esB = (unsigned short*)p;    // [Ntiles*128*128] bf16, swizzled

    hipMemsetAsync(counts, 0, (size_t)N * sizeof(int), stream);

    const int eblocks = (E + 255) / 256;
    const int nblk    = (N + SCAN_B - 1) / SCAN_B;   // 196 <= 256
    const int mblocks = (N + 127) / 128;             // tiles
    const int total   = mblocks * 128;               // padded node rows

    hist_kernel<<<eblocks, 256, 0, stream>>>(eidx, counts, E);
    scan_p1_kernel<<<nblk, SCAN_B, 0, stream>>>(counts, offsets, blockSums, N);
    scan_p2_kernel<<<1, SCAN_B, 0, stream>>>(blockSums, nblk);
    scan_p3_kernel<<<nblk, SCAN_B, 0, stream>>>(offsets, blockSums, cursor, N, E);
    scatter_perm_kernel<<<eblocks, 256, 0, stream>>>(eidx, cursor, perm, E);
    {
        int gthreads = total * 64;
        int gblocks  = (gthreads + 255) / 256;
        gather_bf16_kernel<<<gblocks, 256, 0, stream>>>(eattr, perm, offsets,
                                                        esB, N, total);
    }
    fused_mlp_kernel<<<mblocks, 512, 0, stream>>>(x, esB, W0, b0, W2, b2,
                                                  W3, b3, out, N);
}

// Round 4
// 665.864 us; speedup vs baseline: 1.1799x; 1.0507x over previous
//
#include <hip/hip_runtime.h>
#include <cmath>

typedef __attribute__((ext_vector_type(8))) short bf16x8;
typedef __attribute__((ext_vector_type(4))) float f32x4;
typedef __attribute__((ext_vector_type(4))) unsigned int u32x4;

__device__ __forceinline__ short f2bf(float f) {
    unsigned u = __builtin_bit_cast(unsigned, f);
    u += 0x7fff + ((u >> 16) & 1);   // RNE
    return (short)(u >> 16);
}

__device__ __forceinline__ float4 ntload4(const float* p) {
    f32x4 v = __builtin_nontemporal_load(reinterpret_cast<const f32x4*>(p));
    return make_float4(v.x, v.y, v.z, v.w);
}

// ---------------------------------------------------------------------------
// Counting sort of edges by destination.
// ---------------------------------------------------------------------------
__global__ __launch_bounds__(256)
void hist_kernel(const int* __restrict__ dst, int* __restrict__ counts, int E)
{
    int e = blockIdx.x * 256 + threadIdx.x;
    if (e < E) atomicAdd(&counts[dst[e]], 1);
}

// --- coalesced 3-phase scan over N counts -> offsets[0..N] & cursor ---
#define SCAN_B 256

__global__ __launch_bounds__(SCAN_B)
void scan_p1_kernel(const int* __restrict__ counts, int* __restrict__ offsets,
                    int* __restrict__ blockSums, int N)
{
    __shared__ int sh[SCAN_B];
    const int t = threadIdx.x;
    const int i = blockIdx.x * SCAN_B + t;
    int v = (i < N) ? counts[i] : 0;
    sh[t] = v;
    __syncthreads();
    for (int d = 1; d < SCAN_B; d <<= 1) {
        int u = (t >= d) ? sh[t - d] : 0;
        __syncthreads();
        sh[t] += u;
        __syncthreads();
    }
    if (i < N) offsets[i] = sh[t] - v;           // local exclusive
    if (t == SCAN_B - 1) blockSums[blockIdx.x] = sh[SCAN_B - 1];
}

__global__ __launch_bounds__(SCAN_B)
void scan_p2_kernel(int* __restrict__ blockSums, int nblk)
{
    __shared__ int sh[SCAN_B];
    const int t = threadIdx.x;
    int v = (t < nblk) ? blockSums[t] : 0;
    sh[t] = v;
    __syncthreads();
    for (int d = 1; d < SCAN_B; d <<= 1) {
        int u = (t >= d) ? sh[t - d] : 0;
        __syncthreads();
        sh[t] += u;
        __syncthreads();
    }
    if (t < nblk) blockSums[t] = sh[t] - v;      // exclusive
}

__global__ __launch_bounds__(SCAN_B)
void scan_p3_kernel(int* __restrict__ offsets, const int* __restrict__ blockSums,
                    int* __restrict__ cursor, int N, int E)
{
    const int i = blockIdx.x * SCAN_B + threadIdx.x;
    if (i < N) {
        int o = offsets[i] + blockSums[blockIdx.x];
        offsets[i] = o;
        cursor[i]  = o;
    }
    if (i == 0) offsets[N] = E;
}

__global__ __launch_bounds__(256)
void scatter_perm_kernel(const int* __restrict__ dst, int* __restrict__ cursor,
                         int* __restrict__ perm, int E)
{
    int e = blockIdx.x * 256 + threadIdx.x;
    if (e < E) {
        int p = atomicAdd(&cursor[dst[e]], 1);
        perm[p] = e;
    }
}

// ---------------------------------------------------------------------------
// One-time weight conversion: f32 -> bf16, pre-swizzled into the MFMA tile
// layout the MLP's Wt LDS buffer uses. Tiles: 0=W0[k0:128], 1=W0[k128:256],
// 2=W2, 3=W3. Same index math (and same RNE) as the old in-kernel stage_W,
// so results are bit-identical.
// ---------------------------------------------------------------------------
__global__ __launch_bounds__(512)
void convert_w_kernel(const float* __restrict__ W0, const float* __restrict__ W2,
                      const float* __restrict__ W3, unsigned short* __restrict__ wB)
{
    const int tile = blockIdx.x >> 3;   // 0..3
    const int seg  = blockIdx.x & 7;    // 0..7
    const float* W; int krow0;
    if (tile == 0)      { W = W0; krow0 = 0; }
    else if (tile == 1) { W = W0; krow0 = 128; }
    else if (tile == 2) { W = W2; krow0 = 0; }
    else                { W = W3; krow0 = 0; }
    unsigned short* dst = wB + (size_t)tile * 16384;
    const int tid = threadIdx.x;
    #pragma unroll
    for (int ii = 0; ii < 2; ++ii) {
        int p = tid + (seg * 2 + ii) * 512;
        int n = p & 127;
        int k = (p >> 7) << 1;
        float a = W[(size_t)(krow0 + k) * 128 + n];
        float b = W[(size_t)(krow0 + k + 1) * 128 + n];
        int grp = (k >> 3) ^ (n & 15);
        ushort2 s;
        s.x = (unsigned short)f2bf(a);
        s.y = (unsigned short)f2bf(b);
        *reinterpret_cast<ushort2*>(&dst[n * 128 + grp * 8 + (k & 7)]) = s;
    }
}

// ---------------------------------------------------------------------------
// Gather-sum: one wave per node (high TLP -> BW-bound). Output written as
// bf16 directly in the MLP's swizzled At-tile layout. edge_attr loads are
// non-temporal (read exactly once); esB store stays cacheable (read back by
// the MLP shortly after).
// ---------------------------------------------------------------------------
__global__ __launch_bounds__(256)
void gather_bf16_kernel(const float* __restrict__ edge_attr,
                        const int* __restrict__ perm,
                        const int* __restrict__ offsets,
                        unsigned short* __restrict__ esB, int N, int total)
{
    const int wid  = (blockIdx.x * 256 + threadIdx.x) >> 6;
    const int lane = threadIdx.x & 63;
    if (wid >= total) return;
    const int half = lane >> 5;
    const int li   = lane & 31;

    float4 acc = make_float4(0.f, 0.f, 0.f, 0.f);
    if (wid < N) {
        const int beg = offsets[wid];
        const int end = offsets[wid + 1];
        for (int base = beg; base < end; base += 64) {
            const int m = (end - base < 64) ? (end - base) : 64;
            int eid = 0;
            if (lane < m) eid = perm[base + lane];
            const int pairs = (m + 1) >> 1;
            #pragma unroll 4
            for (int j = 0; j < pairs; ++j) {
                const int idx = 2 * j + half;
                const int e = __shfl(eid, idx, 64);
                if (idx < m) {
                    const float4 v = ntload4(&edge_attr[(size_t)e * 128 + li * 4]);
                    acc.x += v.x; acc.y += v.y; acc.z += v.z; acc.w += v.w;
                }
            }
        }
    }
    // fold upper half into lower half
    float4 o;
    o.x = __shfl(acc.x, li + 32, 64);
    o.y = __shfl(acc.y, li + 32, 64);
    o.z = __shfl(acc.z, li + 32, 64);
    o.w = __shfl(acc.w, li + 32, 64);
    if (half == 0) {
        acc.x += o.x; acc.y += o.y; acc.z += o.z; acc.w += o.w;
        const int r   = wid & 127;
        const int t   = wid >> 7;
        const int grp = (li >> 1) ^ (r & 15);     // c4 = 4*li; grp = (c4>>3)^(r&15)
        ushort4 s;
        s.x = (unsigned short)f2bf(acc.x);
        s.y = (unsigned short)f2bf(acc.y);
        s.z = (unsigned short)f2bf(acc.z);
        s.w = (unsigned short)f2bf(acc.w);
        *reinterpret_cast<ushort4*>(
            &esB[(size_t)t * 16384 + r * 128 + grp * 8 + (li & 1) * 4]) = s;
    }
}

// ---------------------------------------------------------------------------
// Fused 3-layer MLP, bf16 MFMA. Weights arrive pre-swizzled in bf16 (wB);
// each next tile is prefetched into registers before the current MFMA
// section so its latency hides under compute. Half-1 A-tile (esB) is loaded
// at kernel entry (T14 async split).
// ---------------------------------------------------------------------------
__device__ __forceinline__ void ldW(const u32x4* __restrict__ wt, u32x4* wreg, int tid)
{
    #pragma unroll
    for (int i = 0; i < 4; ++i) wreg[i] = wt[i * 512 + tid];
}

__device__ __forceinline__ void stW(short* __restrict__ Wt, const u32x4* wreg, int tid)
{
    u32x4* wv = reinterpret_cast<u32x4*>(Wt);
    #pragma unroll
    for (int i = 0; i < 4; ++i) wv[i * 512 + tid] = wreg[i];
}

__global__ __launch_bounds__(512, 2)
void fused_mlp_kernel(const float* __restrict__ x,
                      const unsigned short* __restrict__ esB,
                      const unsigned short* __restrict__ wB,
                      const float* __restrict__ b0,
                      const float* __restrict__ b2,
                      const float* __restrict__ b3,
                      float* __restrict__ out, int N)
{
    __shared__ short At[128 * 128];
    __shared__ short Wt[128 * 128];

    const int tid  = threadIdx.x;
    const int lane = tid & 63;
    const int wv   = tid >> 6;
    const int l15  = lane & 15;
    const int quad = lane >> 4;
    const int m0   = wv * 16;
    const int blockRow = blockIdx.x * 128;

    f32x4 acc[8];
    #pragma unroll
    for (int nt = 0; nt < 8; ++nt) acc[nt] = (f32x4){0.f, 0.f, 0.f, 0.f};

    const u32x4* wb4 = reinterpret_cast<const u32x4*>(wB);

    // Issue half-1 A-tile loads early (T14 async split): 32 KB linear copy.
    u32x4 es[4];
    {
        const u32x4* esg = reinterpret_cast<const u32x4*>(esB) +
                           (size_t)blockIdx.x * 2048;
        #pragma unroll
        for (int i = 0; i < 4; ++i)
            es[i] = __builtin_nontemporal_load(&esg[i * 512 + tid]);
    }
    u32x4 wreg[4];
    ldW(wb4 + 0 * 2048, wreg, tid);                 // W0 k-tile 0

    // ---------------- half 0: x @ W0[0:128] ----------------
    #pragma unroll
    for (int i = 0; i < 8; ++i) {
        int f  = tid + i * 512;
        int r  = f >> 5;
        int c4 = (f & 31) << 2;
        int g  = blockRow + r; if (g >= N) g = N - 1;
        const float4 v = ntload4(&x[(size_t)g * 128 + c4]);
        int grp = (c4 >> 3) ^ (r & 15);
        ushort4 s;
        s.x = (unsigned short)f2bf(v.x);
        s.y = (unsigned short)f2bf(v.y);
        s.z = (unsigned short)f2bf(v.z);
        s.w = (unsigned short)f2bf(v.w);
        *reinterpret_cast<ushort4*>(&At[r * 128 + grp * 8 + (c4 & 7)]) = s;
    }
    stW(Wt, wreg, tid);
    __syncthreads();
    ldW(wb4 + 1 * 2048, wreg, tid);                 // prefetch W0 k-tile 1
    #pragma unroll
    for (int ks = 0; ks < 4; ++ks) {
        int g = ks * 4 + quad;
        int so = ((g ^ l15) << 3);
        bf16x8 a = *reinterpret_cast<bf16x8*>(&At[(m0 + l15) * 128 + so]);
        #pragma unroll
        for (int nt = 0; nt < 8; ++nt) {
            bf16x8 b = *reinterpret_cast<bf16x8*>(&Wt[(nt * 16 + l15) * 128 + so]);
            acc[nt] = __builtin_amdgcn_mfma_f32_16x16x32_bf16(a, b, acc[nt], 0, 0, 0);
        }
    }
    __syncthreads();   // all waves done reading At/Wt before restage

    // ---------------- half 1: edge_sum @ W0[128:256] ----------------
    {
        u32x4* atv = reinterpret_cast<u32x4*>(At);
        #pragma unroll
        for (int i = 0; i < 4; ++i) atv[i * 512 + tid] = es[i];
    }
    stW(Wt, wreg, tid);
    __syncthreads();
    ldW(wb4 + 2 * 2048, wreg, tid);                 // prefetch W2
    #pragma unroll
    for (int ks = 0; ks < 4; ++ks) {
        int g = ks * 4 + quad;
        int so = ((g ^ l15) << 3);
        bf16x8 a = *reinterpret_cast<bf16x8*>(&At[(m0 + l15) * 128 + so]);
        #pragma unroll
        for (int nt = 0; nt < 8; ++nt) {
            bf16x8 b = *reinterpret_cast<bf16x8*>(&Wt[(nt * 16 + l15) * 128 + so]);
            acc[nt] = __builtin_amdgcn_mfma_f32_16x16x32_bf16(a, b, acc[nt], 0, 0, 0);
        }
    }

    // ---------------- layer 2 ----------------
    __syncthreads();
    #pragma unroll
    for (int nt = 0; nt < 8; ++nt) {
        float bv = b0[nt * 16 + l15];
        #pragma unroll
        for (int r = 0; r < 4; ++r) {
            float v = acc[nt][r] + bv;
            v = (v > 0.f) ? v : (__expf(v) - 1.f);
            int m = m0 + quad * 4 + r;
            int c = nt * 16 + l15;
            int grp = (c >> 3) ^ (m & 15);
            At[m * 128 + grp * 8 + (c & 7)] = f2bf(v);
        }
        acc[nt] = (f32x4){0.f, 0.f, 0.f, 0.f};
    }
    stW(Wt, wreg, tid);
    __syncthreads();
    ldW(wb4 + 3 * 2048, wreg, tid);                 // prefetch W3

    #pragma unroll
    for (int ks = 0; ks < 4; ++ks) {
        int g = ks * 4 + quad;
        int so = ((g ^ l15) << 3);
        bf16x8 a = *reinterpret_cast<bf16x8*>(&At[(m0 + l15) * 128 + so]);
        #pragma unroll
        for (int nt = 0; nt < 8; ++nt) {
            bf16x8 b = *reinterpret_cast<bf16x8*>(&Wt[(nt * 16 + l15) * 128 + so]);
            acc[nt] = __builtin_amdgcn_mfma_f32_16x16x32_bf16(a, b, acc[nt], 0, 0, 0);
        }
    }

    // ---------------- layer 3 ----------------
    __syncthreads();
    #pragma unroll
    for (int nt = 0; nt < 8; ++nt) {
        float bv = b2[nt * 16 + l15];
        #pragma unroll
        for (int r = 0; r < 4; ++r) {
            float v = acc[nt][r] + bv;
            v = (v > 0.f) ? v : (__expf(v) - 1.f);
            int m = m0 + quad * 4 + r;
            int c = nt * 16 + l15;
            int grp = (c >> 3) ^ (m & 15);
            At[m * 128 + grp * 8 + (c & 7)] = f2bf(v);
        }
        acc[nt] = (f32x4){0.f, 0.f, 0.f, 0.f};
    }
    stW(Wt, wreg, tid);
    __syncthreads();

    #pragma unroll
    for (int ks = 0; ks < 4; ++ks) {
        int g = ks * 4 + quad;
        int so = ((g ^ l15) << 3);
        bf16x8 a = *reinterpret_cast<bf16x8*>(&At[(m0 + l15) * 128 + so]);
        #pragma unroll
        for (int nt = 0; nt < 8; ++nt) {
            bf16x8 b = *reinterpret_cast<bf16x8*>(&Wt[(nt * 16 + l15) * 128 + so]);
            acc[nt] = __builtin_amdgcn_mfma_f32_16x16x32_bf16(a, b, acc[nt], 0, 0, 0);
        }
    }

    #pragma unroll
    for (int nt = 0; nt < 8; ++nt) {
        float bv = b3[nt * 16 + l15];
        #pragma unroll
        for (int r = 0; r < 4; ++r) {
            int gr = blockRow + m0 + quad * 4 + r;
            if (gr < N)
                __builtin_nontemporal_store(acc[nt][r] + bv,
                                            &out[(size_t)gr * 128 + nt * 16 + l15]);
        }
    }
}

extern "C" void kernel_launch(void* const* d_in, const int* in_sizes, int n_in,
                              void* d_out, int out_size, void* d_ws, size_t ws_size,
                              hipStream_t stream)
{
    const float* x     = (const float*)d_in[0];
    const int*   eidx  = (const int*)d_in[1];   // row 0 = dst
    const float* eattr = (const float*)d_in[2];
    const float* W0 = (const float*)d_in[3];
    const float* b0 = (const float*)d_in[4];
    const float* W2 = (const float*)d_in[5];
    const float* b2 = (const float*)d_in[6];
    const float* W3 = (const float*)d_in[7];
    const float* b3 = (const float*)d_in[8];
    float* out = (float*)d_out;

    const int N = in_sizes[0] / 128;   // 50000
    const int E = in_sizes[2] / 128;   // 800000

    int* counts    = (int*)d_ws;                 // [N]
    int* offsets   = counts + N;                 // [N+1]
    int* cursor    = offsets + (N + 1);          // [N]
    int* blockSums = cursor + N;                 // [<=256]
    int* perm      = blockSums + 256;            // [E]
    uintptr_t p = (uintptr_t)(perm + E);
    p = (p + 255) & ~(uintptr_t)255;
    unsigned short* esB = (unsigned short*)p;    // [tiles*128*128] bf16, swizzled
    const int mblocks = (N + 127) / 128;         // tiles
    p = (uintptr_t)(esB + (size_t)mblocks * 16384);
    p = (p + 255) & ~(uintptr_t)255;
    unsigned short* wB = (unsigned short*)p;     // [4*128*128] bf16, swizzled

    hipMemsetAsync(counts, 0, (size_t)N * sizeof(int), stream);

    const int eblocks = (E + 255) / 256;
    const int nblk    = (N + SCAN_B - 1) / SCAN_B;   // 196 <= 256
    const int total   = mblocks * 128;               // padded node rows

    convert_w_kernel<<<32, 512, 0, stream>>>(W0, W2, W3, wB);
    hist_kernel<<<eblocks, 256, 0, stream>>>(eidx, counts, E);
    scan_p1_kernel<<<nblk, SCAN_B, 0, stream>>>(counts, offsets, blockSums, N);
    scan_p2_kernel<<<1, SCAN_B, 0, stream>>>(blockSums, nblk);
    scan_p3_kernel<<<nblk, SCAN_B, 0, stream>>>(offsets, blockSums, cursor, N, E);
    scatter_perm_kernel<<<eblocks, 256, 0, stream>>>(eidx, cursor, perm, E);
    {
        int gthreads = total * 64;
        int gblocks  = (gthreads + 255) / 256;
        gather_bf16_kernel<<<gblocks, 256, 0, stream>>>(eattr, perm, offsets,
                                                        esB, N, total);
    }
    fused_mlp_kernel<<<mblocks, 512, 0, stream>>>(x, esB, wB, b0, b2, b3, out, N);
}